// Round 2
// 765.455 us; speedup vs baseline: 1.0408x; 1.0408x over previous
//
#include <hip/hip_runtime.h>
#include <stdint.h>

#define DIM 256
#define TOPK 64
#define HIST_BINS 65536
#define CAP 4096

// Monotone float->uint mapping: a > b  <=>  fkey(a) > fkey(b)
__device__ __forceinline__ uint32_t fkey(float f) {
  uint32_t u = __float_as_uint(f);
  return (u & 0x80000000u) ? ~u : (u | 0x80000000u);
}

// Kernel Z: zero hist + candidate counter. 64 blocks x 256 thr x 16 B = 256 KB.
__global__ __launch_bounds__(256) void zero_kernel(uint32_t* __restrict__ hist,
                                                   int* __restrict__ cnt) {
  int tid = blockIdx.x * 256 + threadIdx.x;
  ((uint4*)hist)[tid] = make_uint4(0u, 0u, 0u, 0u);
  if (tid == 0) *cnt = 0;
}

// Kernel S: scores + fused histogram.
// Grid-stride, 2048 blocks (8/CU -> 32 waves/CU). Each wave handles 4
// contiguous rows per iteration: 16-lane group `sub` owns row r4*4+sub,
// each thread loads 4 independent float4 (64 B) -> 4 loads in flight,
// then a 4-step shfl_xor reduce within the 16-lane group.
__global__ __launch_bounds__(256) void score_kernel(
    const float* __restrict__ mat, const float* __restrict__ query,
    float* __restrict__ scores, uint32_t* __restrict__ hist, int n) {
  const int lane = threadIdx.x & 63;
  const int li = lane & 15;   // position within 16-lane group
  const int sub = lane >> 4;  // which of the wave's 4 rows
  const int gw = blockIdx.x * 4 + (threadIdx.x >> 6);
  const int W = gridDim.x * 4;

  // query fragment for this lane's column slots (L1-resident broadcast)
  float4 q0 = ((const float4*)query)[li];
  float4 q1 = ((const float4*)query)[li + 16];
  float4 q2 = ((const float4*)query)[li + 32];
  float4 q3 = ((const float4*)query)[li + 48];

  int n4 = (n + 3) >> 2;
  for (int r4 = gw; r4 < n4; r4 += W) {
    int row = r4 * 4 + sub;
    float d = 0.f;
    if (row < n) {
      const float4* m4 = (const float4*)(mat + (size_t)row * DIM);
      float4 a = m4[li];
      float4 b = m4[li + 16];
      float4 c = m4[li + 32];
      float4 e = m4[li + 48];
      d = a.x * q0.x + a.y * q0.y + a.z * q0.z + a.w * q0.w;
      d += b.x * q1.x + b.y * q1.y + b.z * q1.z + b.w * q1.w;
      d += c.x * q2.x + c.y * q2.y + c.z * q2.z + c.w * q2.w;
      d += e.x * q3.x + e.y * q3.y + e.z * q3.z + e.w * q3.w;
    }
#pragma unroll
    for (int off = 8; off > 0; off >>= 1) d += __shfl_xor(d, off, 64);
    if (li == 0 && row < n) {
      scores[row] = d;
      atomicAdd(&hist[fkey(d) >> 16], 1u);  // fire-and-forget, no return
    }
  }
}

// Kernel T: single block. Find smallest bin t such that
// (# scores with bin >= t) >= TOPK.  Two-level suffix scan.
__global__ __launch_bounds__(256) void thresh_kernel(
    const uint32_t* __restrict__ hist, int* __restrict__ tbin) {
  __shared__ uint32_t s[256];
  __shared__ int fc;
  __shared__ uint32_t above;
  int t = threadIdx.x;

  uint32_t acc = 0;
  const uint4* h4 = (const uint4*)(hist + t * 256);
  for (int j = 0; j < 64; ++j) {
    uint4 v = h4[j];
    acc += v.x + v.y + v.z + v.w;
  }
  s[t] = acc;
  __syncthreads();
  // inclusive suffix sum over 256 chunk sums
  for (int off = 1; off < 256; off <<= 1) {
    uint32_t v = (t + off < 256) ? s[t + off] : 0u;
    __syncthreads();
    s[t] += v;
    __syncthreads();
  }
  if (s[t] >= TOPK && (t == 255 || s[t + 1] < TOPK)) {
    fc = t;
    above = (t == 255) ? 0u : s[t + 1];
  }
  __syncthreads();
  int c = fc;
  uint32_t a = above;
  uint32_t h = hist[c * 256 + t];
  __syncthreads();
  s[t] = h;
  __syncthreads();
  for (int off = 1; off < 256; off <<= 1) {
    uint32_t v = (t + off < 256) ? s[t + off] : 0u;
    __syncthreads();
    s[t] += v;
    __syncthreads();
  }
  if (a + s[t] >= TOPK && (t == 255 || a + s[t + 1] < TOPK)) {
    *tbin = c * 256 + t;
  }
}

// Kernel C: collect candidates with bin >= threshold.
// Packed key: (monotone score << 32) | ~idx  -> bigger = better, ties -> lower idx.
__global__ __launch_bounds__(256) void collect_kernel(
    const float* __restrict__ scores, const int* __restrict__ tbin,
    int* __restrict__ cnt, unsigned long long* __restrict__ cand, int n) {
  uint32_t T = (uint32_t)(*tbin);
  int i = blockIdx.x * 256 + threadIdx.x;
  int stride = gridDim.x * 256;
  for (; i < n; i += stride) {
    uint32_t key = fkey(scores[i]);
    if ((key >> 16) >= T) {
      int pos = atomicAdd(cnt, 1);
      if (pos < CAP) {
        cand[pos] = ((unsigned long long)key << 32) | (uint32_t)(~(uint32_t)i);
      }
    }
  }
}

// Kernel F: rank candidates (distinct keys -> exact ranks), emit idx (as f32)
// and gather the TOPK rows. 1024 threads: 16 waves x 4 rows for the gather.
__global__ __launch_bounds__(1024) void final_kernel(
    const unsigned long long* __restrict__ cand, const int* __restrict__ cnt,
    const float* __restrict__ mat, float* __restrict__ out) {
  __shared__ unsigned long long c[CAP];
  __shared__ int sel[TOPK];
  int t = threadIdx.x;
  int M = *cnt;
  if (M > CAP) M = CAP;

  for (int i = t; i < M; i += 1024) c[i] = cand[i];
  __syncthreads();

  for (int i = t; i < M; i += 1024) {
    unsigned long long mykey = c[i];
    int rank = 0;
    for (int j = 0; j < M; ++j) rank += (c[j] > mykey) ? 1 : 0;
    if (rank < TOPK) sel[rank] = (int)(~(uint32_t)(mykey & 0xFFFFFFFFull));
  }
  __syncthreads();

  // idx output, written as float32 values
  if (t < TOPK) out[TOPK * DIM + t] = (float)sel[t];

  // gather rows: wave w handles rows w, w+16, ... ; lane l copies float4 block
  int wv = t >> 6, lane = t & 63;
  for (int r = wv; r < TOPK; r += 16) {
    size_t row = (size_t)sel[r];
    float4 v = ((const float4*)(mat + row * DIM))[lane];
    ((float4*)(out + r * DIM))[lane] = v;
  }
}

extern "C" void kernel_launch(void* const* d_in, const int* in_sizes, int n_in,
                              void* d_out, int out_size, void* d_ws, size_t ws_size,
                              hipStream_t stream) {
  const float* query = (const float*)d_in[0];
  const float* mat = (const float*)d_in[1];
  float* out = (float*)d_out;
  int n = in_sizes[1] / DIM;

  char* ws = (char*)d_ws;
  float* scores = (float*)ws;                               // n floats (<2 MB)
  uint32_t* hist = (uint32_t*)(ws + (2u << 20));            // 256 KB
  int* tbin = (int*)(ws + (2u << 20) + HIST_BINS * 4);
  int* cnt = tbin + 1;
  unsigned long long* cand =
      (unsigned long long*)(ws + (2u << 20) + HIST_BINS * 4 + 16);  // CAP*8

  zero_kernel<<<64, 256, 0, stream>>>(hist, cnt);
  score_kernel<<<2048, 256, 0, stream>>>(mat, query, scores, hist, n);
  thresh_kernel<<<1, 256, 0, stream>>>(hist, tbin);
  collect_kernel<<<512, 256, 0, stream>>>(scores, tbin, cnt, cand, n);
  final_kernel<<<1, 1024, 0, stream>>>(cand, cnt, mat, out);
}